// Round 2
// 414.156 us; speedup vs baseline: 1.0706x; 1.0706x over previous
//
#include <hip/hip_runtime.h>

typedef __bf16 bf16x8 __attribute__((ext_vector_type(8)));
typedef __bf16 bf16x2 __attribute__((ext_vector_type(2)));
typedef float f32x4 __attribute__((ext_vector_type(4)));
typedef unsigned u32x4v __attribute__((ext_vector_type(4)));

#define MFMA16(a, b, c) __builtin_amdgcn_mfma_f32_16x16x32_bf16(a, b, c, 0, 0, 0)
#define LOG2E 1.4426950408889634f

typedef __attribute__((address_space(3))) void lds_void;
typedef __attribute__((address_space(1))) const void gbl_void;
__device__ inline void glds16(const __bf16* g, __bf16* l) {
  __builtin_amdgcn_global_load_lds((gbl_void*)g, (lds_void*)l, 16, 0, 0);
}

// bf16-pair unpack helpers: low/high half of a u32 holding two bf16.
__device__ inline float blo(unsigned u) { return __builtin_bit_cast(float, u << 16); }
__device__ inline float bhi(unsigned u) { return __builtin_bit_cast(float, u & 0xffff0000u); }
__device__ inline unsigned pk2(float a, float b) {
  bf16x2 t; t[0] = (__bf16)a; t[1] = (__bf16)b;
  return __builtin_bit_cast(unsigned, t);
}

// Convert f32 -> bf16 with scale, 8 elements per thread.
__global__ void cvt_scale(const float* __restrict__ src, __bf16* __restrict__ dst,
                          int n8, float scale) {
  int i = blockIdx.x * blockDim.x + threadIdx.x;
  if (i >= n8) return;
  const float4* p = (const float4*)(src + i * 8);
  float4 a = p[0], b = p[1];
  bf16x8 r;
  r[0] = (__bf16)(a.x * scale); r[1] = (__bf16)(a.y * scale);
  r[2] = (__bf16)(a.z * scale); r[3] = (__bf16)(a.w * scale);
  r[4] = (__bf16)(b.x * scale); r[5] = (__bf16)(b.y * scale);
  r[6] = (__bf16)(b.z * scale); r[7] = (__bf16)(b.w * scale);
  *(bf16x8*)(dst + i * 8) = r;
}

// Pack rel-pos bias for the swapped (S^T) QK MFMA with PERMUTED key order:
// element v[t2*4+r] at lane (quad,l15) = bias(q = qt*16 + l15,
//   key = tp*32 + quad*8 + t2*4 + r), pre-scaled by log2(e),
// pad (q/key >= 343) baked as -1e30.  This order makes the S^T C-fragment
// directly reusable as the PV A-fragment (no cross-lane transpose).
__global__ void pack_bias(const float* __restrict__ rpb, __bf16* __restrict__ dst) {
  int i = blockIdx.x * blockDim.x + threadIdx.x;
  if (i >= 16 * 15488) return;
  int h = i / 15488, rem = i % 15488;   // 15488 = 22*11*64
  int qt = rem / 704, rem2 = rem % 704; // 704 = 11*64
  int tp = rem2 >> 6, lane = rem2 & 63;
  int quad = lane >> 4, l15 = lane & 15;
  int q = qt * 16 + l15;
  bf16x8 v;
#pragma unroll
  for (int t2 = 0; t2 < 2; t2++)
#pragma unroll
    for (int r = 0; r < 4; r++) {
      int kc = tp * 32 + quad * 8 + t2 * 4 + r;
      float val = -1e30f;
      if (q < 343 && kc < 343) {
        int q0 = q / 49, q1 = (q / 7) % 7, q2 = q % 7;
        int k0 = kc / 49, k1 = (kc / 7) % 7, k2 = kc % 7;
        int idx = ((q0 - k0 + 6) * 13 + (q1 - k1 + 6)) * 13 + (q2 - k2 + 6);
        val = rpb[idx * 16 + h] * LOG2E;
      }
      v[t2 * 4 + r] = (__bf16)val;
    }
  *(bf16x8*)(dst + i * 8) = v;
}

// Same swapped+permuted packing for the window mask: [w][qt][tp][lane][8].
__global__ void pack_mask(const float* __restrict__ mask, __bf16* __restrict__ dst) {
  int i = blockIdx.x * blockDim.x + threadIdx.x;
  if (i >= 64 * 15488) return;
  int w = i / 15488, rem = i % 15488;
  int qt = rem / 704, rem2 = rem % 704;
  int tp = rem2 >> 6, lane = rem2 & 63;
  int quad = lane >> 4, l15 = lane & 15;
  int q = qt * 16 + l15;
  const float* s = mask + w * 117649;
  bf16x8 v;
#pragma unroll
  for (int t2 = 0; t2 < 2; t2++)
#pragma unroll
    for (int r = 0; r < 4; r++) {
      int kc = tp * 32 + quad * 8 + t2 * 4 + r;
      float val = (q < 343 && kc < 343) ? s[q * 343 + kc] * LOG2E : -1e30f;
      v[t2 * 4 + r] = (__bf16)val;
    }
  *(bf16x8*)(dst + i * 8) = v;
}

// C = A(MxK) @ B(NxK)^T, bf16 in, 128x128 tile, BK=32, global_load_lds staging.
// MODE 0: scatter epilogue -> K,V bf16 [b][h][n][hd].  MODE 1: +bias, f32 out.
template <int MODE>
__global__ void __launch_bounds__(256, 2)
gemm_async(const __bf16* __restrict__ A, const __bf16* __restrict__ B, const int K,
           void* __restrict__ out0, void* __restrict__ out1,
           const float* __restrict__ pbias) {
  __shared__ __bf16 As[128 * 32];
  __shared__ __bf16 Bs[128 * 32];
  const int tid = threadIdx.x;
  const int lane = tid & 63, wave = tid >> 6;
  const int quad = lane >> 4, l15 = lane & 15;
  const int wm = wave >> 1, wn = wave & 1;
  const int m0 = blockIdx.y * 128, n0 = blockIdx.x * 128;
  const int sr = lane >> 2, sc = (lane & 3) * 8;
  const __bf16* Ab = A + (m0 + wave * 16 + sr) * K + sc;
  const __bf16* Bb = B + (n0 + wave * 16 + sr) * K + sc;
  __bf16* Asl = As + wave * 512;  // wave-uniform LDS base; HW adds lane*16B
  __bf16* Bsl = Bs + wave * 512;
  f32x4 acc[4][4] = {};
  for (int k0 = 0; k0 < K; k0 += 32) {
    glds16(Ab + k0, Asl);
    glds16(Ab + 64 * K + k0, Asl + 2048);
    glds16(Bb + k0, Bsl);
    glds16(Bb + 64 * K + k0, Bsl + 2048);
    __syncthreads();  // drains vmcnt -> staged data visible
    bf16x8 af[4], bfr[4];
#pragma unroll
    for (int i = 0; i < 4; i++) {
      af[i] = *(const bf16x8*)(As + (wm * 64 + i * 16 + l15) * 32 + quad * 8);
      bfr[i] = *(const bf16x8*)(Bs + (wn * 64 + i * 16 + l15) * 32 + quad * 8);
    }
#pragma unroll
    for (int i = 0; i < 4; i++)
#pragma unroll
      for (int j = 0; j < 4; j++)
        acc[i][j] = MFMA16(af[i], bfr[j], acc[i][j]);
    __syncthreads();  // protect LDS before next stage
  }
#pragma unroll
  for (int i = 0; i < 4; i++) {
    const int rowb = m0 + wm * 64 + i * 16 + quad * 4;
#pragma unroll
    for (int r = 0; r < 4; r++) {
      const int row = rowb + r;
      if constexpr (MODE == 0) {
        const int bb = row / 343, pos = row % 343;
#pragma unroll
        for (int j = 0; j < 4; j++) {
          const int col = n0 + wn * 64 + j * 16 + l15;
          const int two = col >> 9, hh = (col >> 5) & 15, d = col & 31;
          __bf16* dst = two ? (__bf16*)out1 : (__bf16*)out0;
          dst[((bb * 16 + hh) * 343 + pos) * 32 + d] = (__bf16)acc[i][j][r];
        }
      } else {
        float* o = (float*)out0;
#pragma unroll
        for (int j = 0; j < 4; j++) {
          const int col = n0 + wn * 64 + j * 16 + l15;
          o[row * 512 + col] = acc[i][j][r] + pbias[col];
        }
      }
    }
  }
}

// One workgroup per (b, h). Swapped QK^T (S^T = mfma(K, Q)) with PERMUTED key
// order (bk0 rows = (l15>>2)*8+(l15&3), bk1 +4) so the S^T C-fragment IS the
// PV A-fragment after bf16 packing: zero cross-lane ops, zero LDS staging of P.
// 32-key chunks streamed (s0,s1 only -> low regs). Softmax denominator via an
// extra "ones-column" MFMA. Outer loop over key-chunks: K/V LDS fragments
// reused across 3 q-tiles/wave.
__global__ void __launch_bounds__(512, 2)
attn_win(const __bf16* __restrict__ qs, const __bf16* __restrict__ kk,
         const __bf16* __restrict__ vv, const __bf16* __restrict__ bias_pk,
         const __bf16* __restrict__ mask_pk, __bf16* __restrict__ ao) {
  __shared__ __bf16 Ks[352 * 40];    // keys padded to 352 rows, stride 40
  __shared__ __bf16 Vt[32 * 360];    // V transposed [hd][key], stride 360
  const int bh = blockIdx.x;
  const int b = bh >> 4, h = bh & 15;
  const int tid = threadIdx.x;
  const int lane = tid & 63, wave = tid >> 6;
  const int quad = lane >> 4, l15 = lane & 15;
  const __bf16* ksrc = kk + (b * 16 + h) * 10976;
  const __bf16* vsrc = vv + (b * 16 + h) * 10976;
  for (int i = tid; i < 352 * 4; i += 512) {
    const int row = i >> 2, seg = (i & 3) * 8;
    bf16x8 val;
    if (row < 343) {
      val = *(const bf16x8*)(ksrc + row * 32 + seg);
    } else {
#pragma unroll
      for (int e = 0; e < 8; e++) val[e] = (__bf16)0.f;
    }
    *(bf16x8*)(Ks + row * 40 + seg) = val;
  }
  // zero-pad Vt cols 343..358 (reads reach col 351)
  Vt[(tid >> 4) * 360 + 343 + (tid & 15)] = (__bf16)0.f;
  for (int i = tid; i < 1372; i += 512) {  // 10976/8 vectorized transpose
    const int pos = i >> 2, seg = (i & 3) * 8;
    bf16x8 v = *(const bf16x8*)(vsrc + pos * 32 + seg);
#pragma unroll
    for (int e = 0; e < 8; e++) Vt[(seg + e) * 360 + pos] = v[e];
  }

  const int b2 = b >> 6, w = b & 63;
  const __bf16* qbase = qs + (b2 * 16 + h) * 10976;
  const __bf16* bpk = bias_pk + h * 123904;  // 22*11*64*8
  const __bf16* mpk = mask_pk + w * 123904;
  const int nqt = (wave < 6) ? 3 : 2;  // 22 q-tiles over 8 waves

  bf16x8 aq[3];
#pragma unroll
  for (int t = 0; t < 3; t++) {
    int qt = wave + 8 * t; if (qt > 21) qt = 21;
    const int arow = qt * 16 + l15;
    const int arowc = arow < 343 ? arow : 342;  // clamp; padded rows discarded
    aq[t] = *(const bf16x8*)(qbase + arowc * 32 + quad * 8);
  }
  bf16x8 ones;  // B-frag of the "ones column": col 0 = 1, rest 0
  {
    const __bf16 ov = (l15 == 0) ? (__bf16)1.f : (__bf16)0.f;
#pragma unroll
    for (int e = 0; e < 8; e++) ones[e] = ov;
  }
  const int krow = (l15 >> 2) * 8 + (l15 & 3);  // permuted key-row order
  __syncthreads();

  f32x4 o0[3], o1[3], o2[3];
#pragma unroll
  for (int t = 0; t < 3; t++)
#pragma unroll
    for (int r = 0; r < 4; r++) { o0[t][r] = 0.f; o1[t][r] = 0.f; o2[t][r] = 0.f; }

  for (int c = 0; c < 11; c++) {  // 11 chunks of 32 keys
    const bf16x8 bk0 = *(const bf16x8*)(Ks + (c * 32 + krow) * 40 + quad * 8);
    const bf16x8 bk1 = *(const bf16x8*)(Ks + (c * 32 + krow + 4) * 40 + quad * 8);
    const bf16x8 bv0 = *(const bf16x8*)(Vt + l15 * 360 + c * 32 + quad * 8);
    const bf16x8 bv1 = *(const bf16x8*)(Vt + (16 + l15) * 360 + c * 32 + quad * 8);
    const __bf16* bq = bpk + c * 512 + lane * 8;
    const __bf16* mq = mpk + c * 512 + lane * 8;
#pragma unroll
    for (int t = 0; t < 3; t++) {
      if (t >= nqt) break;
      const int qoff = (wave + 8 * t) * 5632;  // 11*64*8
      const uint4 bu = *(const uint4*)(bq + qoff);
      const uint4 mu = *(const uint4*)(mq + qoff);
      f32x4 s0, s1;  // C preloaded with bias+mask (log2 domain), S^T layout
      s0[0] = blo(bu.x) + blo(mu.x); s0[1] = bhi(bu.x) + bhi(mu.x);
      s0[2] = blo(bu.y) + blo(mu.y); s0[3] = bhi(bu.y) + bhi(mu.y);
      s1[0] = blo(bu.z) + blo(mu.z); s1[1] = bhi(bu.z) + bhi(mu.z);
      s1[2] = blo(bu.w) + blo(mu.w); s1[3] = bhi(bu.w) + bhi(mu.w);
      s0 = MFMA16(bk0, aq[t], s0);  // swapped: rows=keys (permuted), cols=q
      s1 = MFMA16(bk1, aq[t], s1);
#pragma unroll
      for (int r = 0; r < 4; r++) {
        s0[r] = __builtin_amdgcn_exp2f(s0[r]);
        s1[r] = __builtin_amdgcn_exp2f(s1[r]);
      }
      // S^T fragment (permuted key order) IS the PV A-fragment: just pack.
      u32x4v uv;
      uv[0] = pk2(s0[0], s0[1]); uv[1] = pk2(s0[2], s0[3]);
      uv[2] = pk2(s1[0], s1[1]); uv[3] = pk2(s1[2], s1[3]);
      const bf16x8 ap = __builtin_bit_cast(bf16x8, uv);
      o0[t] = MFMA16(ap, bv0, o0[t]);
      o1[t] = MFMA16(ap, bv1, o1[t]);
      o2[t] = MFMA16(ap, ones, o2[t]);  // row-sum of P via matrix pipe
    }
  }

#pragma unroll
  for (int t = 0; t < 3; t++) {
    if (t >= nqt) break;
    const int qt = wave + 8 * t;
#pragma unroll
    for (int r = 0; r < 4; r++) {
      const float lsum = __shfl(o2[t][r], lane & 48);  // from l15==0 of my quad
      const float inv = __builtin_amdgcn_rcpf(lsum);
      const int row = qt * 16 + quad * 4 + r;
      if (row < 343) {
        __bf16* op = ao + (b * 343 + row) * 512 + h * 32;
        op[l15] = (__bf16)(o0[t][r] * inv);
        op[16 + l15] = (__bf16)(o1[t][r] * inv);
      }
    }
  }
}

extern "C" void kernel_launch(void* const* d_in, const int* in_sizes, int n_in,
                              void* d_out, int out_size, void* d_ws, size_t ws_size,
                              hipStream_t stream) {
  (void)in_sizes; (void)n_in; (void)out_size; (void)ws_size;
  const float* x      = (const float*)d_in[0];
  const float* mask   = (const float*)d_in[4];
  const float* qg     = (const float*)d_in[5];
  const float* kv_w   = (const float*)d_in[6];
  const float* proj_w = (const float*)d_in[7];
  const float* proj_b = (const float*)d_in[8];
  const float* rpb    = (const float*)d_in[9];

  // Workspace layout (16B aligned), total 156,973,056 B. aob aliases xb
  // (xb dead after gemm1; attn writes aob only after gemm1 completes).
  char* ws = (char*)d_ws;
  __bf16* q_bf    = (__bf16*)(ws);               //    702,464  q*scale*log2e [2][16][343][32]
  __bf16* bias_pk = (__bf16*)(ws + 702464);      //  3,964,928  [16][22][11][64][8]
  __bf16* mask_pk = (__bf16*)(ws + 4667392);     // 15,859,712  [64][22][11][64][8]
  __bf16* kvw_b   = (__bf16*)(ws + 20527104);    //  1,048,576
  __bf16* projw_b = (__bf16*)(ws + 21575680);    //    524,288
  __bf16* kb      = (__bf16*)(ws + 22099968);    // 44,957,696  K bf16 [128][16][343][32]
  __bf16* vb      = (__bf16*)(ws + 67057664);    // 44,957,696  V bf16
  __bf16* xb      = (__bf16*)(ws + 112015360);   // 44,957,696  x bf16
  __bf16* aob     = (__bf16*)(ws + 112015360);   // alias: attn out bf16

  const float QSCALE = 0.17677669529663687f * LOG2E;  // hd^-0.5 * log2(e)

  cvt_scale<<<172, 256, 0, stream>>>(qg, q_bf, 43904, QSCALE);   // 351,232 elems = 43904*8
  cvt_scale<<<10976, 256, 0, stream>>>(x, xb, 2809856, 1.f);
  cvt_scale<<<256, 256, 0, stream>>>(kv_w, kvw_b, 65536, 1.f);
  cvt_scale<<<128, 256, 0, stream>>>(proj_w, projw_b, 32768, 1.f);
  pack_bias<<<968, 256, 0, stream>>>(rpb, bias_pk);
  pack_mask<<<3872, 256, 0, stream>>>(mask, mask_pk);
  gemm_async<0><<<dim3(8, 343), 256, 0, stream>>>(xb, kvw_b, 512, kb, vb, nullptr);
  attn_win<<<2048, 512, 0, stream>>>(q_bf, kb, vb, bias_pk, mask_pk, aob);
  gemm_async<1><<<dim3(4, 343), 256, 0, stream>>>(aob, projw_b, 512, d_out, nullptr, proj_b);
}